// Round 2
// baseline (1144.726 us; speedup 1.0000x reference)
//
#include <hip/hip_runtime.h>

#define B_ 4
#define S_ 2048
#define D_ 1024
#define H_ 8
#define HD_ 128
#define FF_ 4096
#define R_ (B_*S_)          // 8192 rows

typedef __attribute__((ext_vector_type(8))) short short8;
typedef __attribute__((ext_vector_type(4))) float f32x4;

__device__ __forceinline__ unsigned short f2bf(float f) {
  unsigned int u = __float_as_uint(f);
  return (unsigned short)((u + 0x7fffu + ((u >> 16) & 1u)) >> 16);
}
__device__ __forceinline__ float bf2f(unsigned short s) {
  return __uint_as_float(((unsigned int)s) << 16);
}

// ---------- transpose + f32->bf16: dst[c][r] = bf16(src[r][c]) ----------
__global__ __launch_bounds__(256) void f2bf_t(const float* __restrict__ src,
    unsigned short* __restrict__ dst, int Rows, int Cols) {
  __shared__ float tile[32][33];
  const int tx = threadIdx.x & 31, ty = threadIdx.x >> 5;   // ty in 0..7
  const int r0 = blockIdx.y * 32, c0 = blockIdx.x * 32;
  #pragma unroll
  for (int j = 0; j < 32; j += 8)
    tile[ty + j][tx] = src[(size_t)(r0 + ty + j) * Cols + c0 + tx];
  __syncthreads();
  #pragma unroll
  for (int j = 0; j < 32; j += 8)
    dst[(size_t)(c0 + ty + j) * Rows + r0 + tx] = f2bf(tile[tx][ty + j]);
}

// ---------- RMSNorm f32 in -> bf16 out (one block per row of 1024) ----------
__global__ __launch_bounds__(256) void rmsnorm_f2b(const float* __restrict__ in,
    const float* __restrict__ w, unsigned short* __restrict__ out, float eps) {
  const int row = blockIdx.x, t = threadIdx.x;
  const float4 xv = *(const float4*)&in[(size_t)row * D_ + t * 4];
  float p = xv.x*xv.x + xv.y*xv.y + xv.z*xv.z + xv.w*xv.w;
  #pragma unroll
  for (int off = 32; off >= 1; off >>= 1) p += __shfl_xor(p, off);
  __shared__ float red[4];
  if ((t & 63) == 0) red[t >> 6] = p;
  __syncthreads();
  float scl = rsqrtf((red[0] + red[1] + red[2] + red[3]) * (1.0f / D_) + eps);
  const float4 wv = *(const float4*)&w[t * 4];
  ((ushort4*)out)[(size_t)row * 256 + t] = make_ushort4(
      f2bf(xv.x*scl*wv.x), f2bf(xv.y*scl*wv.y), f2bf(xv.z*scl*wv.z), f2bf(xv.w*scl*wv.w));
}

// ---------- RMSNorm bf16 in -> bf16 out (qk-norm, eps 1e-6), in-place safe ----------
__global__ __launch_bounds__(256) void rmsnorm_b2b(const unsigned short* __restrict__ in,
    const float* __restrict__ w, unsigned short* __restrict__ out, float eps) {
  const int row = blockIdx.x, t = threadIdx.x;
  const ushort4 xv = ((const ushort4*)in)[(size_t)row * 256 + t];
  float x0 = bf2f(xv.x), x1 = bf2f(xv.y), x2 = bf2f(xv.z), x3 = bf2f(xv.w);
  float p = x0*x0 + x1*x1 + x2*x2 + x3*x3;
  #pragma unroll
  for (int off = 32; off >= 1; off >>= 1) p += __shfl_xor(p, off);
  __shared__ float red[4];
  if ((t & 63) == 0) red[t >> 6] = p;
  __syncthreads();
  float scl = rsqrtf((red[0] + red[1] + red[2] + red[3]) * (1.0f / D_) + eps);
  const float4 wv = *(const float4*)&w[t * 4];
  ((ushort4*)out)[(size_t)row * 256 + t] = make_ushort4(
      f2bf(x0*scl*wv.x), f2bf(x1*scl*wv.y), f2bf(x2*scl*wv.z), f2bf(x3*scl*wv.w));
}

// ---------- residual: h(f32) += sc[ch] * bf16(p) ----------
__global__ void resid_k(float* __restrict__ h, const unsigned short* __restrict__ p,
                        const float* __restrict__ sc, int n4) {
  int i = blockIdx.x * blockDim.x + threadIdx.x;
  int st = gridDim.x * blockDim.x;
  for (; i < n4; i += st) {
    float4 hv = ((float4*)h)[i];
    ushort4 pv = ((const ushort4*)p)[i];
    float4 sv = ((const float4*)sc)[i & (D_/4 - 1)];
    hv.x += sv.x * bf2f(pv.x); hv.y += sv.y * bf2f(pv.y);
    hv.z += sv.z * bf2f(pv.z); hv.w += sv.w * bf2f(pv.w);
    ((float4*)h)[i] = hv;
  }
}

// ---------- windowed ALiBi attention: 1 wave per (b,h,i), bf16 in/out ----------
__global__ __launch_bounds__(256) void attn_k(const unsigned short* __restrict__ q,
    const unsigned short* __restrict__ k, const unsigned short* __restrict__ v,
    unsigned short* __restrict__ y) {
  const int lane = threadIdx.x & 63;
  const int wid = (blockIdx.x * 256 + threadIdx.x) >> 6;
  const int i  = wid & (S_ - 1);
  const int bh = wid >> 11;
  const int hh = bh & (H_ - 1);
  const int b  = bh >> 3;
  const float slope = exp2f(-(float)(hh + 1));
  const float inv = 0.088388347648318447f;          // 1/sqrt(128)
  const size_t qoff = ((size_t)(b * S_ + i)) * (H_*HD_) + hh * HD_ + lane * 2;
  const ushort2 qv = *(const ushort2*)&q[qoff];
  const float qx = bf2f(qv.x), qy = bf2f(qv.y);
  float sc[17];
  #pragma unroll
  for (int jj = 0; jj < 17; ++jj) {
    int j = i - 16 + jj;
    int jc = j < 0 ? 0 : j;
    size_t koff = ((size_t)(b * S_ + jc)) * (H_*HD_) + hh * HD_ + lane * 2;
    ushort2 kv = *(const ushort2*)&k[koff];
    float p = qx * bf2f(kv.x) + qy * bf2f(kv.y);
    p += __shfl_xor(p, 32); p += __shfl_xor(p, 16); p += __shfl_xor(p, 8);
    p += __shfl_xor(p, 4);  p += __shfl_xor(p, 2);  p += __shfl_xor(p, 1);
    sc[jj] = (j >= 0) ? (p * inv + slope * (float)(jj - 16)) : -1e30f;
  }
  float m = sc[0];
  #pragma unroll
  for (int jj = 1; jj < 17; ++jj) m = fmaxf(m, sc[jj]);
  float wsum = 0.f, ax = 0.f, ay = 0.f;
  #pragma unroll
  for (int jj = 0; jj < 17; ++jj) {
    int j = i - 16 + jj;
    int jc = j < 0 ? 0 : j;
    float wgt = expf(sc[jj] - m);
    size_t voff = ((size_t)(b * S_ + jc)) * (H_*HD_) + hh * HD_ + lane * 2;
    ushort2 vv = *(const ushort2*)&v[voff];
    wsum += wgt; ax += wgt * bf2f(vv.x); ay += wgt * bf2f(vv.y);
  }
  float rs = 1.f / wsum;
  *(ushort2*)&y[qoff] = make_ushort2(f2bf(ax * rs), f2bf(ay * rs));
}

// ---------- bf16 MFMA GEMM: C[M,N](bf16) = A[M,K] @ Bt[N,K]^T ----------
// 128x128 tile, 4 waves of 64x64, mfma_f32_16x16x32_bf16, BK=32
__global__ __launch_bounds__(256, 2) void gemm_tn(
    const unsigned short* __restrict__ A, const unsigned short* __restrict__ Bt,
    unsigned short* __restrict__ C, int M, int N, int K) {
  __shared__ __align__(16) unsigned short As[128][40];
  __shared__ __align__(16) unsigned short Bs[128][40];
  const int t = threadIdx.x;
  const int lane = t & 63, w = t >> 6;
  const int wr = w >> 1, wc = w & 1;
  const int br = blockIdx.y * 128, bc = blockIdx.x * 128;
  const int lr = lane & 15, lk = lane >> 4;
  f32x4 acc[4][4];
  #pragma unroll
  for (int mi = 0; mi < 4; ++mi)
    #pragma unroll
    for (int ni = 0; ni < 4; ++ni) { f32x4 z = {0.f,0.f,0.f,0.f}; acc[mi][ni] = z; }
  for (int k0 = 0; k0 < K; k0 += 32) {
    #pragma unroll
    for (int it = 0; it < 2; ++it) {
      int idx = t + it * 256;
      int r = idx >> 2, c8 = (idx & 3) * 8;
      *(int4*)&As[r][c8] = *(const int4*)&A[(size_t)(br + r) * K + k0 + c8];
      *(int4*)&Bs[r][c8] = *(const int4*)&Bt[(size_t)(bc + r) * K + k0 + c8];
    }
    __syncthreads();
    short8 af[4], bfr[4];
    #pragma unroll
    for (int mi = 0; mi < 4; ++mi)
      af[mi] = *(const short8*)&As[wr * 64 + mi * 16 + lr][lk * 8];
    #pragma unroll
    for (int ni = 0; ni < 4; ++ni)
      bfr[ni] = *(const short8*)&Bs[wc * 64 + ni * 16 + lr][lk * 8];
    #pragma unroll
    for (int mi = 0; mi < 4; ++mi)
      #pragma unroll
      for (int ni = 0; ni < 4; ++ni)
        acc[mi][ni] = __builtin_amdgcn_mfma_f32_16x16x32_bf16(af[mi], bfr[ni], acc[mi][ni], 0, 0, 0);
    __syncthreads();
  }
  #pragma unroll
  for (int mi = 0; mi < 4; ++mi)
    #pragma unroll
    for (int ni = 0; ni < 4; ++ni) {
      int row = br + wr * 64 + mi * 16 + lk * 4;
      int col = bc + wc * 64 + ni * 16 + lr;
      #pragma unroll
      for (int r = 0; r < 4; ++r)
        C[(size_t)(row + r) * N + col] = f2bf(acc[mi][ni][r]);
    }
}

// ---------- fused FFN gate: G = bf16( silu(A@W1t^T) * (A@W3t^T) ) ----------
__global__ __launch_bounds__(256, 2) void gemm_w13(
    const unsigned short* __restrict__ A, const unsigned short* __restrict__ B1t,
    const unsigned short* __restrict__ B3t, unsigned short* __restrict__ G,
    int M, int N, int K) {
  __shared__ __align__(16) unsigned short As[128][40];
  __shared__ __align__(16) unsigned short B1s[128][40];
  __shared__ __align__(16) unsigned short B3s[128][40];
  const int t = threadIdx.x;
  const int lane = t & 63, w = t >> 6;
  const int wr = w >> 1, wc = w & 1;
  const int br = blockIdx.y * 128, bc = blockIdx.x * 128;
  const int lr = lane & 15, lk = lane >> 4;
  f32x4 acc1[4][4], acc3[4][4];
  #pragma unroll
  for (int mi = 0; mi < 4; ++mi)
    #pragma unroll
    for (int ni = 0; ni < 4; ++ni) {
      f32x4 z = {0.f,0.f,0.f,0.f}; acc1[mi][ni] = z; acc3[mi][ni] = z;
    }
  for (int k0 = 0; k0 < K; k0 += 32) {
    #pragma unroll
    for (int it = 0; it < 2; ++it) {
      int idx = t + it * 256;
      int r = idx >> 2, c8 = (idx & 3) * 8;
      *(int4*)&As[r][c8]  = *(const int4*)&A[(size_t)(br + r) * K + k0 + c8];
      *(int4*)&B1s[r][c8] = *(const int4*)&B1t[(size_t)(bc + r) * K + k0 + c8];
      *(int4*)&B3s[r][c8] = *(const int4*)&B3t[(size_t)(bc + r) * K + k0 + c8];
    }
    __syncthreads();
    short8 af[4], b1r[4], b3r[4];
    #pragma unroll
    for (int mi = 0; mi < 4; ++mi)
      af[mi] = *(const short8*)&As[wr * 64 + mi * 16 + lr][lk * 8];
    #pragma unroll
    for (int ni = 0; ni < 4; ++ni) {
      b1r[ni] = *(const short8*)&B1s[wc * 64 + ni * 16 + lr][lk * 8];
      b3r[ni] = *(const short8*)&B3s[wc * 64 + ni * 16 + lr][lk * 8];
    }
    #pragma unroll
    for (int mi = 0; mi < 4; ++mi)
      #pragma unroll
      for (int ni = 0; ni < 4; ++ni) {
        acc1[mi][ni] = __builtin_amdgcn_mfma_f32_16x16x32_bf16(af[mi], b1r[ni], acc1[mi][ni], 0, 0, 0);
        acc3[mi][ni] = __builtin_amdgcn_mfma_f32_16x16x32_bf16(af[mi], b3r[ni], acc3[mi][ni], 0, 0, 0);
      }
    __syncthreads();
  }
  #pragma unroll
  for (int mi = 0; mi < 4; ++mi)
    #pragma unroll
    for (int ni = 0; ni < 4; ++ni) {
      int row = br + wr * 64 + mi * 16 + lk * 4;
      int col = bc + wc * 64 + ni * 16 + lr;
      #pragma unroll
      for (int r = 0; r < 4; ++r) {
        float a1 = acc1[mi][ni][r], a3 = acc3[mi][ni][r];
        float g = a1 / (1.f + expf(-a1)) * a3;
        G[(size_t)(row + r) * N + col] = f2bf(g);
      }
    }
}

extern "C" void kernel_launch(void* const* d_in, const int* in_sizes, int n_in,
                              void* d_out, int out_size, void* d_ws, size_t ws_size,
                              hipStream_t stream) {
  const float* x    = (const float*)d_in[0];
  const float* wq   = (const float*)d_in[1];
  const float* wk   = (const float*)d_in[2];
  const float* wv   = (const float*)d_in[3];
  const float* wo   = (const float*)d_in[4];
  const float* qnw  = (const float*)d_in[5];
  const float* knw  = (const float*)d_in[6];
  const float* w1   = (const float*)d_in[7];
  const float* w2   = (const float*)d_in[8];
  const float* w3   = (const float*)d_in[9];
  const float* anw  = (const float*)d_in[10];
  const float* fnw  = (const float*)d_in[11];
  const float* asc  = (const float*)d_in[12];
  const float* fsc  = (const float*)d_in[13];

  const size_t MB = 1024 * 1024;
  if (ws_size < 144 * MB) return;   // diagnostic guard: fail validation, don't fault

  float* h = (float*)d_out;
  char* ws = (char*)d_ws;
  // [0,64MB): transposed bf16 weights
  unsigned short* wqt = (unsigned short*)ws;          // L x [1024][1024]
  unsigned short* wkt = wqt + 2u * 1048576u;
  unsigned short* wvt = wkt + 2u * 1048576u;
  unsigned short* wot = wvt + 2u * 1048576u;
  unsigned short* w1t = wot + 2u * 1048576u;          // L x [4096][1024]
  unsigned short* w3t = w1t + 2u * 4194304u;
  unsigned short* w2t = w3t + 2u * 4194304u;          // L x [1024][4096]
  // activation slots
  unsigned short* xn   = (unsigned short*)(ws + 64 * MB);   // 16MB: xnorm / attn-y / w2out
  unsigned short* q    = (unsigned short*)(ws + 80 * MB);   // 16MB
  unsigned short* kbuf = (unsigned short*)(ws + 96 * MB);   // 16MB
  unsigned short* v    = (unsigned short*)(ws + 112 * MB);  // 16MB
  unsigned short* proj = (unsigned short*)(ws + 128 * MB);  // 16MB
  unsigned short* gate = q;                                 // 64MB span (q..proj)

  hipMemcpyAsync(h, x, (size_t)R_ * D_ * sizeof(float), hipMemcpyDeviceToDevice, stream);

  for (int l = 0; l < 2; ++l) {
    f2bf_t<<<dim3(32, 32),  256, 0, stream>>>(wq + (size_t)l*1048576, wqt + (size_t)l*1048576, 1024, 1024);
    f2bf_t<<<dim3(32, 32),  256, 0, stream>>>(wk + (size_t)l*1048576, wkt + (size_t)l*1048576, 1024, 1024);
    f2bf_t<<<dim3(32, 32),  256, 0, stream>>>(wv + (size_t)l*1048576, wvt + (size_t)l*1048576, 1024, 1024);
    f2bf_t<<<dim3(32, 32),  256, 0, stream>>>(wo + (size_t)l*1048576, wot + (size_t)l*1048576, 1024, 1024);
    f2bf_t<<<dim3(128, 32), 256, 0, stream>>>(w1 + (size_t)l*4194304, w1t + (size_t)l*4194304, 1024, 4096);
    f2bf_t<<<dim3(128, 32), 256, 0, stream>>>(w3 + (size_t)l*4194304, w3t + (size_t)l*4194304, 1024, 4096);
    f2bf_t<<<dim3(32, 128), 256, 0, stream>>>(w2 + (size_t)l*4194304, w2t + (size_t)l*4194304, 4096, 1024);
  }

  for (int l = 0; l < 2; ++l) {
    // ---- attention ----
    rmsnorm_f2b<<<R_, 256, 0, stream>>>(h, anw + l * D_, xn, 0.01f);
    gemm_tn<<<dim3(8, 64), 256, 0, stream>>>(xn, wqt + (size_t)l*1048576, q,    R_, 1024, 1024);
    gemm_tn<<<dim3(8, 64), 256, 0, stream>>>(xn, wkt + (size_t)l*1048576, kbuf, R_, 1024, 1024);
    gemm_tn<<<dim3(8, 64), 256, 0, stream>>>(xn, wvt + (size_t)l*1048576, v,    R_, 1024, 1024);
    rmsnorm_b2b<<<R_, 256, 0, stream>>>(q,    qnw + l * 1024, q,    1e-6f);
    rmsnorm_b2b<<<R_, 256, 0, stream>>>(kbuf, knw + l * 1024, kbuf, 1e-6f);
    attn_k<<<R_ * H_ / 4, 256, 0, stream>>>(q, kbuf, v, xn);   // y overwrites xn (dead)
    gemm_tn<<<dim3(8, 64), 256, 0, stream>>>(xn, wot + (size_t)l*1048576, proj, R_, 1024, 1024);
    resid_k<<<2048, 256, 0, stream>>>(h, proj, asc + l * D_, R_ * D_ / 4);
    // ---- FFN ----
    rmsnorm_f2b<<<R_, 256, 0, stream>>>(h, fnw + l * D_, xn, 0.01f);
    gemm_w13<<<dim3(32, 64), 256, 0, stream>>>(xn, w1t + (size_t)l*4194304,
                                               w3t + (size_t)l*4194304, gate, R_, 4096, 1024);
    gemm_tn<<<dim3(8, 64), 256, 0, stream>>>(gate, w2t + (size_t)l*4194304, xn, R_, 1024, 4096);
    resid_k<<<2048, 256, 0, stream>>>(h, xn, fsc + l * D_, R_ * D_ / 4);
  }
}

// Round 3
// 910.487 us; speedup vs baseline: 1.2573x; 1.2573x over previous
//
#include <hip/hip_runtime.h>

#define B_ 4
#define S_ 2048
#define D_ 1024
#define H_ 8
#define HD_ 128
#define FF_ 4096
#define R_ (B_*S_)          // 8192 rows

typedef __attribute__((ext_vector_type(8))) short short8;
typedef __attribute__((ext_vector_type(4))) float f32x4;

__device__ __forceinline__ unsigned short f2bf(float f) {
  unsigned int u = __float_as_uint(f);
  return (unsigned short)((u + 0x7fffu + ((u >> 16) & 1u)) >> 16);
}
__device__ __forceinline__ float bf2f(unsigned short s) {
  return __uint_as_float(((unsigned int)s) << 16);
}

typedef const __attribute__((address_space(1))) unsigned int* gas_p;
typedef __attribute__((address_space(3))) unsigned int* las_p;
__device__ __forceinline__ void gload16(const void* g, void* l) {
  __builtin_amdgcn_global_load_lds((gas_p)g, (las_p)l, 16, 0, 0);
}

// ---------- transpose + f32->bf16: dst[c*Rows + r] = bf16(src[r*Cols + c]) ----------
__global__ __launch_bounds__(256) void f2bf_t(const float* __restrict__ src,
    unsigned short* __restrict__ dst, int Rows, int Cols) {
  __shared__ float tile[32][33];
  const int tx = threadIdx.x & 31, ty = threadIdx.x >> 5;
  const int r0 = blockIdx.y * 32, c0 = blockIdx.x * 32;
  #pragma unroll
  for (int j = 0; j < 32; j += 8)
    tile[ty + j][tx] = src[(size_t)(r0 + ty + j) * Cols + c0 + tx];
  __syncthreads();
  #pragma unroll
  for (int j = 0; j < 32; j += 8)
    dst[(size_t)(c0 + ty + j) * Rows + r0 + tx] = f2bf(tile[tx][ty + j]);
}

// ---------- RMSNorm f32 in -> bf16 out (one block per row of 1024) ----------
__global__ __launch_bounds__(256) void rmsnorm_f2b(const float* __restrict__ in,
    const float* __restrict__ w, unsigned short* __restrict__ out, float eps) {
  const int row = blockIdx.x, t = threadIdx.x;
  const float4 xv = *(const float4*)&in[(size_t)row * D_ + t * 4];
  float p = xv.x*xv.x + xv.y*xv.y + xv.z*xv.z + xv.w*xv.w;
  #pragma unroll
  for (int off = 32; off >= 1; off >>= 1) p += __shfl_xor(p, off);
  __shared__ float red[4];
  if ((t & 63) == 0) red[t >> 6] = p;
  __syncthreads();
  float scl = rsqrtf((red[0] + red[1] + red[2] + red[3]) * (1.0f / D_) + eps);
  const float4 wv = *(const float4*)&w[t * 4];
  ((ushort4*)out)[(size_t)row * 256 + t] = make_ushort4(
      f2bf(xv.x*scl*wv.x), f2bf(xv.y*scl*wv.y), f2bf(xv.z*scl*wv.z), f2bf(xv.w*scl*wv.w));
}

// ---------- fused q/k RMSNorm over the 1024-wide flat projection, in-place ----------
__global__ __launch_bounds__(256) void qknorm_k(unsigned short* __restrict__ qkv,
    const float* __restrict__ qw, const float* __restrict__ kw) {
  const int row = blockIdx.x, t = threadIdx.x;
  unsigned short* qp = qkv + (size_t)row * 3072;
  unsigned short* kp = qp + 1024;
  const ushort4 qv = ((const ushort4*)qp)[t];
  const ushort4 kv = ((const ushort4*)kp)[t];
  float q0 = bf2f(qv.x), q1 = bf2f(qv.y), q2 = bf2f(qv.z), q3 = bf2f(qv.w);
  float k0 = bf2f(kv.x), k1 = bf2f(kv.y), k2 = bf2f(kv.z), k3 = bf2f(kv.w);
  float pq = q0*q0 + q1*q1 + q2*q2 + q3*q3;
  float pk = k0*k0 + k1*k1 + k2*k2 + k3*k3;
  #pragma unroll
  for (int off = 32; off >= 1; off >>= 1) { pq += __shfl_xor(pq, off); pk += __shfl_xor(pk, off); }
  __shared__ float redq[4], redk[4];
  if ((t & 63) == 0) { redq[t >> 6] = pq; redk[t >> 6] = pk; }
  __syncthreads();
  float sq = rsqrtf((redq[0]+redq[1]+redq[2]+redq[3]) * (1.0f / D_) + 1e-6f);
  float sk = rsqrtf((redk[0]+redk[1]+redk[2]+redk[3]) * (1.0f / D_) + 1e-6f);
  const float4 qwv = *(const float4*)&qw[t * 4];
  const float4 kwv = *(const float4*)&kw[t * 4];
  ((ushort4*)qp)[t] = make_ushort4(f2bf(q0*sq*qwv.x), f2bf(q1*sq*qwv.y),
                                   f2bf(q2*sq*qwv.z), f2bf(q3*sq*qwv.w));
  ((ushort4*)kp)[t] = make_ushort4(f2bf(k0*sk*kwv.x), f2bf(k1*sk*kwv.y),
                                   f2bf(k2*sk*kwv.z), f2bf(k3*sk*kwv.w));
}

// ---------- windowed ALiBi attention: 1 wave per (b,h,i); q/k/v packed [8192][3072] ----------
__global__ __launch_bounds__(256) void attn_k(const unsigned short* __restrict__ qkv,
    unsigned short* __restrict__ y) {
  const int lane = threadIdx.x & 63;
  const int wid = (blockIdx.x * 256 + threadIdx.x) >> 6;
  const int i  = wid & (S_ - 1);
  const int bh = wid >> 11;
  const int hh = bh & (H_ - 1);
  const int b  = bh >> 3;
  const float slope = exp2f(-(float)(hh + 1));
  const float inv = 0.088388347648318447f;          // 1/sqrt(128)
  const size_t rowq = ((size_t)(b * S_ + i)) * 3072 + hh * HD_ + lane * 2;
  const ushort2 qv = *(const ushort2*)&qkv[rowq];
  const float qx = bf2f(qv.x), qy = bf2f(qv.y);
  float sc[17];
  #pragma unroll
  for (int jj = 0; jj < 17; ++jj) {
    int j = i - 16 + jj;
    int jc = j < 0 ? 0 : j;
    size_t koff = ((size_t)(b * S_ + jc)) * 3072 + 1024 + hh * HD_ + lane * 2;
    ushort2 kv = *(const ushort2*)&qkv[koff];
    float p = qx * bf2f(kv.x) + qy * bf2f(kv.y);
    p += __shfl_xor(p, 32); p += __shfl_xor(p, 16); p += __shfl_xor(p, 8);
    p += __shfl_xor(p, 4);  p += __shfl_xor(p, 2);  p += __shfl_xor(p, 1);
    sc[jj] = (j >= 0) ? (p * inv + slope * (float)(jj - 16)) : -1e30f;
  }
  float m = sc[0];
  #pragma unroll
  for (int jj = 1; jj < 17; ++jj) m = fmaxf(m, sc[jj]);
  float wsum = 0.f, ax = 0.f, ay = 0.f;
  #pragma unroll
  for (int jj = 0; jj < 17; ++jj) {
    int j = i - 16 + jj;
    int jc = j < 0 ? 0 : j;
    float wgt = expf(sc[jj] - m);
    size_t voff = ((size_t)(b * S_ + jc)) * 3072 + 2048 + hh * HD_ + lane * 2;
    ushort2 vv = *(const ushort2*)&qkv[voff];
    wsum += wgt; ax += wgt * bf2f(vv.x); ay += wgt * bf2f(vv.y);
  }
  float rs = 1.f / wsum;
  size_t yoff = ((size_t)(b * S_ + i)) * 1024 + hh * HD_ + lane * 2;
  *(ushort2*)&y[yoff] = make_ushort2(f2bf(ax * rs), f2bf(ay * rs));
}

// ======== MFMA GEMMs: C[M,N] = A[M,K] @ Bt[N,K]^T ========
// 128x128 tile, 4 waves 64x64 each, BK=64, global_load_lds staging with
// both-sides XOR swizzle: phys_slot = slot ^ (row&7)  (slot = 16B granule in row)

// stage one [128][64]-bf16 tile (16KB): 4 gload16 per thread
__device__ __forceinline__ void stage_tile(const unsigned short* __restrict__ src,
    unsigned short* lds, int rowbase, int K, int k0, int t) {
  #pragma unroll
  for (int it = 0; it < 4; ++it) {
    int g = it * 256 + t;
    int row = g >> 3, slot = g & 7;
    int sc8 = (slot ^ (row & 7)) << 3;
    gload16(&src[(size_t)(rowbase + row) * K + k0 + sc8], &lds[g * 8]);
  }
}

__global__ __launch_bounds__(256, 2) void gemm_tn(
    const unsigned short* __restrict__ A, const unsigned short* __restrict__ Bt,
    unsigned short* __restrict__ C, int M, int N, int K) {
  __shared__ __align__(16) unsigned short As[128 * 64];
  __shared__ __align__(16) unsigned short Bs[128 * 64];
  const int t = threadIdx.x;
  const int lane = t & 63, w = t >> 6;
  const int wr = w >> 1, wc = w & 1;
  const int br = blockIdx.y * 128, bc = blockIdx.x * 128;
  const int lr = lane & 15, lk = lane >> 4;
  const int xm = lr & 7;
  f32x4 acc[4][4];
  #pragma unroll
  for (int mi = 0; mi < 4; ++mi)
    #pragma unroll
    for (int ni = 0; ni < 4; ++ni) { f32x4 z = {0.f,0.f,0.f,0.f}; acc[mi][ni] = z; }
  for (int k0 = 0; k0 < K; k0 += 64) {
    stage_tile(A,  As, br, K, k0, t);
    stage_tile(Bt, Bs, bc, K, k0, t);
    __syncthreads();
    #pragma unroll
    for (int kk = 0; kk < 2; ++kk) {
      short8 af[4], bfr[4];
      #pragma unroll
      for (int mi = 0; mi < 4; ++mi)
        af[mi] = *(const short8*)&As[(wr*64 + mi*16 + lr) * 64 + (((kk*4 + lk) ^ xm) << 3)];
      #pragma unroll
      for (int ni = 0; ni < 4; ++ni)
        bfr[ni] = *(const short8*)&Bs[(wc*64 + ni*16 + lr) * 64 + (((kk*4 + lk) ^ xm) << 3)];
      #pragma unroll
      for (int mi = 0; mi < 4; ++mi)
        #pragma unroll
        for (int ni = 0; ni < 4; ++ni)
          acc[mi][ni] = __builtin_amdgcn_mfma_f32_16x16x32_bf16(af[mi], bfr[ni], acc[mi][ni], 0, 0, 0);
    }
    __syncthreads();
  }
  #pragma unroll
  for (int mi = 0; mi < 4; ++mi)
    #pragma unroll
    for (int ni = 0; ni < 4; ++ni) {
      int row = br + wr * 64 + mi * 16 + lk * 4;
      int col = bc + wc * 64 + ni * 16 + lr;
      #pragma unroll
      for (int r = 0; r < 4; ++r)
        C[(size_t)(row + r) * N + col] = f2bf(acc[mi][ni][r]);
    }
}

// same GEMM but epilogue: h[row][col] += sc[col] * acc   (f32 h, N==1024 out cols)
__global__ __launch_bounds__(256, 2) void gemm_ep(
    const unsigned short* __restrict__ A, const unsigned short* __restrict__ Bt,
    float* __restrict__ h, const float* __restrict__ sc, int M, int N, int K) {
  __shared__ __align__(16) unsigned short As[128 * 64];
  __shared__ __align__(16) unsigned short Bs[128 * 64];
  const int t = threadIdx.x;
  const int lane = t & 63, w = t >> 6;
  const int wr = w >> 1, wc = w & 1;
  const int br = blockIdx.y * 128, bc = blockIdx.x * 128;
  const int lr = lane & 15, lk = lane >> 4;
  const int xm = lr & 7;
  f32x4 acc[4][4];
  #pragma unroll
  for (int mi = 0; mi < 4; ++mi)
    #pragma unroll
    for (int ni = 0; ni < 4; ++ni) { f32x4 z = {0.f,0.f,0.f,0.f}; acc[mi][ni] = z; }
  for (int k0 = 0; k0 < K; k0 += 64) {
    stage_tile(A,  As, br, K, k0, t);
    stage_tile(Bt, Bs, bc, K, k0, t);
    __syncthreads();
    #pragma unroll
    for (int kk = 0; kk < 2; ++kk) {
      short8 af[4], bfr[4];
      #pragma unroll
      for (int mi = 0; mi < 4; ++mi)
        af[mi] = *(const short8*)&As[(wr*64 + mi*16 + lr) * 64 + (((kk*4 + lk) ^ xm) << 3)];
      #pragma unroll
      for (int ni = 0; ni < 4; ++ni)
        bfr[ni] = *(const short8*)&Bs[(wc*64 + ni*16 + lr) * 64 + (((kk*4 + lk) ^ xm) << 3)];
      #pragma unroll
      for (int mi = 0; mi < 4; ++mi)
        #pragma unroll
        for (int ni = 0; ni < 4; ++ni)
          acc[mi][ni] = __builtin_amdgcn_mfma_f32_16x16x32_bf16(af[mi], bfr[ni], acc[mi][ni], 0, 0, 0);
    }
    __syncthreads();
  }
  #pragma unroll
  for (int ni = 0; ni < 4; ++ni) {
    int col = bc + wc * 64 + ni * 16 + lr;
    float sv = sc[col];
    #pragma unroll
    for (int mi = 0; mi < 4; ++mi) {
      int row = br + wr * 64 + mi * 16 + lk * 4;
      #pragma unroll
      for (int r = 0; r < 4; ++r)
        h[(size_t)(row + r) * N + col] += sv * acc[mi][ni][r];
    }
  }
}

// fused FFN gate: G = bf16( silu(A@W1t^T) * (A@W3t^T) )
__global__ __launch_bounds__(256, 2) void gemm_w13(
    const unsigned short* __restrict__ A, const unsigned short* __restrict__ B1t,
    const unsigned short* __restrict__ B3t, unsigned short* __restrict__ G,
    int M, int N, int K) {
  __shared__ __align__(16) unsigned short As[128 * 64];
  __shared__ __align__(16) unsigned short B1s[128 * 64];
  __shared__ __align__(16) unsigned short B3s[128 * 64];
  const int t = threadIdx.x;
  const int lane = t & 63, w = t >> 6;
  const int wr = w >> 1, wc = w & 1;
  const int br = blockIdx.y * 128, bc = blockIdx.x * 128;
  const int lr = lane & 15, lk = lane >> 4;
  const int xm = lr & 7;
  f32x4 acc1[4][4], acc3[4][4];
  #pragma unroll
  for (int mi = 0; mi < 4; ++mi)
    #pragma unroll
    for (int ni = 0; ni < 4; ++ni) {
      f32x4 z = {0.f,0.f,0.f,0.f}; acc1[mi][ni] = z; acc3[mi][ni] = z;
    }
  for (int k0 = 0; k0 < K; k0 += 64) {
    stage_tile(A,   As,  br, K, k0, t);
    stage_tile(B1t, B1s, bc, K, k0, t);
    stage_tile(B3t, B3s, bc, K, k0, t);
    __syncthreads();
    #pragma unroll
    for (int kk = 0; kk < 2; ++kk) {
      short8 af[4], b1r[4], b3r[4];
      #pragma unroll
      for (int mi = 0; mi < 4; ++mi)
        af[mi] = *(const short8*)&As[(wr*64 + mi*16 + lr) * 64 + (((kk*4 + lk) ^ xm) << 3)];
      #pragma unroll
      for (int ni = 0; ni < 4; ++ni) {
        b1r[ni] = *(const short8*)&B1s[(wc*64 + ni*16 + lr) * 64 + (((kk*4 + lk) ^ xm) << 3)];
        b3r[ni] = *(const short8*)&B3s[(wc*64 + ni*16 + lr) * 64 + (((kk*4 + lk) ^ xm) << 3)];
      }
      #pragma unroll
      for (int mi = 0; mi < 4; ++mi)
        #pragma unroll
        for (int ni = 0; ni < 4; ++ni) {
          acc1[mi][ni] = __builtin_amdgcn_mfma_f32_16x16x32_bf16(af[mi], b1r[ni], acc1[mi][ni], 0, 0, 0);
          acc3[mi][ni] = __builtin_amdgcn_mfma_f32_16x16x32_bf16(af[mi], b3r[ni], acc3[mi][ni], 0, 0, 0);
        }
    }
    __syncthreads();
  }
  #pragma unroll
  for (int mi = 0; mi < 4; ++mi)
    #pragma unroll
    for (int ni = 0; ni < 4; ++ni) {
      int row = br + wr * 64 + mi * 16 + lk * 4;
      int col = bc + wc * 64 + ni * 16 + lr;
      #pragma unroll
      for (int r = 0; r < 4; ++r) {
        float a1 = acc1[mi][ni][r], a3 = acc3[mi][ni][r];
        G[(size_t)(row + r) * N + col] = f2bf(a1 / (1.f + expf(-a1)) * a3);
      }
    }
}

extern "C" void kernel_launch(void* const* d_in, const int* in_sizes, int n_in,
                              void* d_out, int out_size, void* d_ws, size_t ws_size,
                              hipStream_t stream) {
  const float* x    = (const float*)d_in[0];
  const float* wq   = (const float*)d_in[1];
  const float* wk   = (const float*)d_in[2];
  const float* wv   = (const float*)d_in[3];
  const float* wo   = (const float*)d_in[4];
  const float* qnw  = (const float*)d_in[5];
  const float* knw  = (const float*)d_in[6];
  const float* w1   = (const float*)d_in[7];
  const float* w2   = (const float*)d_in[8];
  const float* w3   = (const float*)d_in[9];
  const float* anw  = (const float*)d_in[10];
  const float* fnw  = (const float*)d_in[11];
  const float* asc  = (const float*)d_in[12];
  const float* fsc  = (const float*)d_in[13];

  const size_t MB = 1024 * 1024;
  if (ws_size < 144 * MB) return;

  float* h = (float*)d_out;
  char* ws = (char*)d_ws;
  // [0,64MB) transposed bf16 weights
  unsigned short* qkvt = (unsigned short*)ws;             // L x [3072][1024]
  unsigned short* wot  = qkvt + 2u * 3145728u;            // L x [1024][1024]
  unsigned short* w1t  = wot  + 2u * 1048576u;            // L x [4096][1024]
  unsigned short* w3t  = w1t  + 2u * 4194304u;
  unsigned short* w2t  = w3t  + 2u * 4194304u;            // L x [1024][4096]
  // activations
  unsigned short* xn   = (unsigned short*)(ws + 64 * MB); // 16MB: xnorm / attn-y
  unsigned short* qkv  = (unsigned short*)(ws + 80 * MB); // 48MB [8192][3072]
  unsigned short* gate = qkv;                             // 64MB [8192][4096] (qkv dead)

  hipMemcpyAsync(h, x, (size_t)R_ * D_ * sizeof(float), hipMemcpyDeviceToDevice, stream);

  for (int l = 0; l < 2; ++l) {
    unsigned short* qkvt_l = qkvt + (size_t)l * 3145728u;
    f2bf_t<<<dim3(32, 32),  256, 0, stream>>>(wq + (size_t)l*1048576, qkvt_l,            1024, 1024);
    f2bf_t<<<dim3(32, 32),  256, 0, stream>>>(wk + (size_t)l*1048576, qkvt_l + 1048576,  1024, 1024);
    f2bf_t<<<dim3(32, 32),  256, 0, stream>>>(wv + (size_t)l*1048576, qkvt_l + 2097152,  1024, 1024);
    f2bf_t<<<dim3(32, 32),  256, 0, stream>>>(wo + (size_t)l*1048576, wot + (size_t)l*1048576, 1024, 1024);
    f2bf_t<<<dim3(128, 32), 256, 0, stream>>>(w1 + (size_t)l*4194304, w1t + (size_t)l*4194304, 1024, 4096);
    f2bf_t<<<dim3(128, 32), 256, 0, stream>>>(w3 + (size_t)l*4194304, w3t + (size_t)l*4194304, 1024, 4096);
    f2bf_t<<<dim3(32, 128), 256, 0, stream>>>(w2 + (size_t)l*4194304, w2t + (size_t)l*4194304, 4096, 1024);
  }

  for (int l = 0; l < 2; ++l) {
    // ---- attention ----
    rmsnorm_f2b<<<R_, 256, 0, stream>>>(h, anw + l * D_, xn, 0.01f);
    gemm_tn<<<dim3(24, 64), 256, 0, stream>>>(xn, qkvt + (size_t)l*3145728u, qkv, R_, 3072, 1024);
    qknorm_k<<<R_, 256, 0, stream>>>(qkv, qnw + l * 1024, knw + l * 1024);
    attn_k<<<R_ * H_ / 4, 256, 0, stream>>>(qkv, xn);
    gemm_ep<<<dim3(8, 64), 256, 0, stream>>>(xn, wot + (size_t)l*1048576u, h, asc + l * D_,
                                             R_, 1024, 1024);
    // ---- FFN ----
    rmsnorm_f2b<<<R_, 256, 0, stream>>>(h, fnw + l * D_, xn, 0.01f);
    gemm_w13<<<dim3(32, 64), 256, 0, stream>>>(xn, w1t + (size_t)l*4194304u,
                                               w3t + (size_t)l*4194304u, gate, R_, 4096, 1024);
    gemm_ep<<<dim3(8, 64), 256, 0, stream>>>(gate, w2t + (size_t)l*4194304u, h, fsc + l * D_,
                                             R_, 1024, 4096);
  }
}